// Round 4
// baseline (300.399 us; speedup 1.0000x reference)
//
#include <hip/hip_runtime.h>
#include <hip/hip_bf16.h>

typedef __attribute__((ext_vector_type(8))) short bshort8;      // 8 bf16 (4 VGPR) MFMA frag
typedef __attribute__((ext_vector_type(4))) float f32x4;        // MFMA accumulator
typedef __attribute__((ext_vector_type(4))) float vfloat4;
typedef __attribute__((ext_vector_type(4))) unsigned int vuint4;
typedef __attribute__((ext_vector_type(2))) unsigned int vuint2;

__device__ __forceinline__ unsigned short f2bf(float f) {
    union { float f; unsigned u; } v; v.f = f;
    unsigned u = v.u;
    u += 0x7fffu + ((u >> 16) & 1u);   // round-to-nearest-even
    return (unsigned short)(u >> 16);
}

// ---------------------------------------------------------------------------
// Generic C = A[M][K] @ Bt[N][K]^T  (Bt stored [N][K], bf16), MFMA 16x16x32.
// Tile: BM=64, BN=64, BK=32; 4 waves in 2x2; wave tile 32x32 (acc 2x2 frags).
// EPI: 0 = fp32 store, 1 = bf16 store
// ---------------------------------------------------------------------------
template<int EPI>
__global__ __launch_bounds__(256)
void gemm_bt(const unsigned short* __restrict__ Av, const unsigned short* __restrict__ Btv,
             void* __restrict__ Cv,
             int M, int N, int K)
{
    __shared__ __align__(128) char sA[64 * 64];   // 64 rows x 32 bf16 (64B/row)
    __shared__ __align__(128) char sB[64 * 64];

    const int tid  = threadIdx.x;
    const int bRow = blockIdx.y << 6;
    const int bCol = blockIdx.x << 6;
    const int wid  = tid >> 6, lane = tid & 63;
    const int wr   = wid >> 1, wc   = wid & 1;
    const int r16  = lane & 15, kg  = lane >> 4;
    const int srow = tid >> 2,  skc = tid & 3;     // staging: row 0..63, k-chunk 0..3

    f32x4 acc[2][2] = {};

    const size_t aRowBase = (size_t)(bRow + srow) * K + skc * 8;
    const size_t bRowBase = (size_t)(bCol + srow) * K + skc * 8;
    // swizzled LDS byte offset for (row, kchunk): bijective XOR, same fn on R/W
    const unsigned swW = ((((unsigned)srow) << 6) | (((unsigned)skc) << 4))
                         ^ ((((unsigned)srow) & 7u) << 4);

    for (int k0 = 0; k0 < K; k0 += 32) {
        vuint4 apack = *(const vuint4*)(Av + aRowBase + k0);
        vuint4 bpack = *(const vuint4*)(Btv + bRowBase + k0);
        *(vuint4*)(sA + swW) = apack;
        *(vuint4*)(sB + swW) = bpack;
        __syncthreads();

        bshort8 af[2], bfr[2];
        #pragma unroll
        for (int mi = 0; mi < 2; mi++) {
            unsigned row = (unsigned)(wr * 32 + mi * 16 + r16);
            unsigned off = ((row << 6) | (((unsigned)kg) << 4)) ^ ((row & 7u) << 4);
            af[mi] = *(const bshort8*)(sA + off);
        }
        #pragma unroll
        for (int ni = 0; ni < 2; ni++) {
            unsigned col = (unsigned)(wc * 32 + ni * 16 + r16);
            unsigned off = ((col << 6) | (((unsigned)kg) << 4)) ^ ((col & 7u) << 4);
            bfr[ni] = *(const bshort8*)(sB + off);
        }
        #pragma unroll
        for (int mi = 0; mi < 2; mi++)
            #pragma unroll
            for (int ni = 0; ni < 2; ni++)
                acc[mi][ni] = __builtin_amdgcn_mfma_f32_16x16x32_bf16(
                                  af[mi], bfr[ni], acc[mi][ni], 0, 0, 0);
        __syncthreads();
    }

    // Epilogue. D frag: col = lane&15, row = (lane>>4)*4 + r  [verified layout]
    #pragma unroll
    for (int mi = 0; mi < 2; mi++) {
        const int row0 = bRow + wr * 32 + mi * 16 + kg * 4;
        #pragma unroll
        for (int ni = 0; ni < 2; ni++) {
            const int col = bCol + wc * 32 + ni * 16 + r16;
            #pragma unroll
            for (int r = 0; r < 4; r++) {
                const int row = row0 + r;
                float x = acc[mi][ni][r];
                const size_t ci = (size_t)row * N + col;
                if constexpr (EPI == 0) ((float*)Cv)[ci] = x;
                else                    ((unsigned short*)Cv)[ci] = f2bf(x);
            }
        }
    }
}

// ---------------------------------------------------------------------------
// Flash attention v2, f-projection fused. Per block: 32 Q-rows of one batch.
//   f = x @ wf (K=512), S = f @ g^T (K=64), P = exp(S), y = (P@h)/rowsum(P)
// x: [8][4096][512] fp32, wft: [64][512] bf16, g: [8][1024][64] bf16,
// ht: [8][256][1024] bf16, y: [8][4096][256] bf16
// 4 waves 2x2. Grid flat 1024; batch = bid&7 (XCD-local KV).
// LDS 44.4KB -> 3 blocks/CU.
// ---------------------------------------------------------------------------
__global__ __launch_bounds__(256)
void flash_attn(const float* __restrict__ x,
                const unsigned short* __restrict__ wft,
                const unsigned short* __restrict__ gb,
                const unsigned short* __restrict__ ht,
                unsigned short* __restrict__ yb)
{
    __shared__ __align__(128) char sS[32 * 128];    // f tile, then P tile
    __shared__ __align__(128) char sG[64 * 128];    // wf chunk (f-phase) / g chunk (KV)
    __shared__ __align__(128) char sH[256 * 128];   // x chunk (f-phase) / ht chunk (KV)
    __shared__ float rs[32];

    const int tid = threadIdx.x;
    const int bid = blockIdx.x;
    const int b   = bid & 7;           // batch == XCD slot (L2-local KV)
    const int q0  = (bid >> 3) << 5;   // 32 q-rows per block
    const int wid = tid >> 6, lane = tid & 63;
    const int wr  = wid >> 1, wc = wid & 1;
    const int r16 = lane & 15, kg = lane >> 4;

    const float*          xB = x  + ((size_t)b * 4096 + q0) * 512;
    const unsigned short* gB = gb + (size_t)b * 1024 * 64;
    const unsigned short* hB = ht + (size_t)b * 256 * 1024;

    // ================= f = x @ wf  (32 x 64, K=512, BK=64) =================
    f32x4 facc[2] = {};
    {
        const int xrow = tid >> 3, xc8 = tid & 7;    // x: 32 rows x 8 chunks(8 fp32)
        const int wrow = tid >> 2, wk0 = tid & 3;    // wf_t: 64 rows x chunks
        for (int k0 = 0; k0 < 512; k0 += 64) {
            {   // stage x chunk -> sH (bf16, 128B rows, swizzled)
                const float* p = xB + (size_t)xrow * 512 + k0 + xc8 * 8;
                vfloat4 a0 = *(const vfloat4*)p;
                vfloat4 a1 = *(const vfloat4*)(p + 4);
                vuint4 w;
                w[0] = (unsigned)f2bf(a0[0]) | ((unsigned)f2bf(a0[1]) << 16);
                w[1] = (unsigned)f2bf(a0[2]) | ((unsigned)f2bf(a0[3]) << 16);
                w[2] = (unsigned)f2bf(a1[0]) | ((unsigned)f2bf(a1[1]) << 16);
                w[3] = (unsigned)f2bf(a1[2]) | ((unsigned)f2bf(a1[3]) << 16);
                unsigned off = ((unsigned)xrow * 128 + (unsigned)xc8 * 16)
                               ^ (((unsigned)xrow & 7u) << 4);
                *(vuint4*)(sH + off) = w;
            }
            #pragma unroll
            for (int it = 0; it < 2; it++) {   // stage wf chunk -> sG
                const int skc = wk0 + it * 4;
                vuint4 v = *(const vuint4*)(wft + (size_t)wrow * 512 + k0 + skc * 8);
                unsigned off = ((unsigned)wrow * 128 + (unsigned)skc * 16)
                               ^ (((unsigned)wrow & 7u) << 4);
                *(vuint4*)(sG + off) = v;
            }
            __syncthreads();

            bshort8 ax0, ax1;
            {
                unsigned row = (unsigned)(wr * 16 + r16);
                unsigned base = row * 128, sw = (row & 7u) << 4;
                ax0 = *(const bshort8*)(sH + ((base + (unsigned)kg * 16) ^ sw));
                ax1 = *(const bshort8*)(sH + ((base + 64 + (unsigned)kg * 16) ^ sw));
            }
            #pragma unroll
            for (int ni = 0; ni < 2; ni++) {
                unsigned col = (unsigned)(wc * 32 + ni * 16 + r16);
                unsigned base = col * 128, sw = (col & 7u) << 4;
                bshort8 b0 = *(const bshort8*)(sG + ((base + (unsigned)kg * 16) ^ sw));
                bshort8 b1 = *(const bshort8*)(sG + ((base + 64 + (unsigned)kg * 16) ^ sw));
                facc[ni] = __builtin_amdgcn_mfma_f32_16x16x32_bf16(ax0, b0, facc[ni], 0, 0, 0);
                facc[ni] = __builtin_amdgcn_mfma_f32_16x16x32_bf16(ax1, b1, facc[ni], 0, 0, 0);
            }
            __syncthreads();
        }
    }

    // ---- redistribute f: C-layout acc -> sS (bf16) -> A-layout frags ----
    #pragma unroll
    for (int ni = 0; ni < 2; ni++) {
        const unsigned col = (unsigned)(wc * 32 + ni * 16 + r16);
        #pragma unroll
        for (int r = 0; r < 4; r++) {
            unsigned row = (unsigned)(wr * 16 + kg * 4 + r);
            unsigned off = (row * 128 + col * 2) ^ ((row & 7u) << 4);
            *(unsigned short*)(sS + off) = f2bf(facc[ni][r]);
        }
    }
    __syncthreads();
    bshort8 af[2];
    {
        unsigned row = (unsigned)(wr * 16 + r16);
        unsigned base = row * 128, sw = (row & 7u) << 4;
        af[0] = *(const bshort8*)(sS + ((base + (unsigned)kg * 16) ^ sw));
        af[1] = *(const bshort8*)(sS + ((base + 64 + (unsigned)kg * 16) ^ sw));
    }

    // ================= KV loop =================
    f32x4 yacc[8] = {};
    float psum[4] = {};
    const int kc = tid & 7, n0 = tid >> 3;   // staging coords

    for (int c = 0; c < 16; c++) {
        const int kv0 = c << 6;
        #pragma unroll
        for (int it = 0; it < 2; it++) {     // stage g chunk [64 keys][64 d]
            const int n = n0 + it * 32;
            vuint4 v = *(const vuint4*)(gB + (size_t)(kv0 + n) * 64 + kc * 8);
            unsigned off = ((unsigned)n * 128 + (unsigned)kc * 16) ^ (((unsigned)n & 7u) << 4);
            *(vuint4*)(sG + off) = v;
        }
        #pragma unroll
        for (int it = 0; it < 8; it++) {     // stage ht chunk [256 n][64 k]
            const int n = n0 + it * 32;
            vuint4 v = *(const vuint4*)(hB + (size_t)n * 1024 + kv0 + kc * 8);
            unsigned off = ((unsigned)n * 128 + (unsigned)kc * 16) ^ (((unsigned)n & 7u) << 4);
            *(vuint4*)(sH + off) = v;
        }
        __syncthreads();   // af-read (c==0) / previous PV complete before reuse

        // ---- QK: S = f @ g^T ----
        f32x4 sacc[2] = {};
        #pragma unroll
        for (int ni = 0; ni < 2; ni++) {
            unsigned col = (unsigned)(wc * 32 + ni * 16 + r16);
            unsigned base = col * 128, sw = (col & 7u) << 4;
            bshort8 g0 = *(const bshort8*)(sG + ((base + (unsigned)kg * 16) ^ sw));
            bshort8 g1 = *(const bshort8*)(sG + ((base + 64 + (unsigned)kg * 16) ^ sw));
            sacc[ni] = __builtin_amdgcn_mfma_f32_16x16x32_bf16(af[0], g0, sacc[ni], 0, 0, 0);
            sacc[ni] = __builtin_amdgcn_mfma_f32_16x16x32_bf16(af[1], g1, sacc[ni], 0, 0, 0);
        }

        // ---- exp, rowsum partials, write P tile to sS ----
        #pragma unroll
        for (int ni = 0; ni < 2; ni++) {
            const unsigned col = (unsigned)(wc * 32 + ni * 16 + r16);
            #pragma unroll
            for (int r = 0; r < 4; r++) {
                float e = __expf(sacc[ni][r]);
                psum[r] += e;
                unsigned row = (unsigned)(wr * 16 + kg * 4 + r);
                unsigned off = (row * 128 + col * 2) ^ ((row & 7u) << 4);
                *(unsigned short*)(sS + off) = f2bf(e);
            }
        }
        __syncthreads();

        // ---- PV: yacc += P @ h ----
        bshort8 pa0, pa1;
        {
            unsigned row = (unsigned)(wr * 16 + r16);
            unsigned base = row * 128, sw = (row & 7u) << 4;
            pa0 = *(const bshort8*)(sS + ((base + (unsigned)kg * 16) ^ sw));
            pa1 = *(const bshort8*)(sS + ((base + 64 + (unsigned)kg * 16) ^ sw));
        }
        #pragma unroll
        for (int ni = 0; ni < 8; ni++) {
            unsigned col = (unsigned)(wc * 128 + ni * 16 + r16);
            unsigned base = col * 128, sw = (col & 7u) << 4;
            bshort8 b0 = *(const bshort8*)(sH + ((base + (unsigned)kg * 16) ^ sw));
            bshort8 b1 = *(const bshort8*)(sH + ((base + 64 + (unsigned)kg * 16) ^ sw));
            yacc[ni] = __builtin_amdgcn_mfma_f32_16x16x32_bf16(pa0, b0, yacc[ni], 0, 0, 0);
            yacc[ni] = __builtin_amdgcn_mfma_f32_16x16x32_bf16(pa1, b1, yacc[ni], 0, 0, 0);
        }
        __syncthreads();
    }

    // ---- rowsum: reduce across the 16 lanes of each row-group, then waves ----
    #pragma unroll
    for (int r = 0; r < 4; r++) {
        float s = psum[r];
        s += __shfl_xor(s, 1, 64);
        s += __shfl_xor(s, 2, 64);
        s += __shfl_xor(s, 4, 64);
        s += __shfl_xor(s, 8, 64);
        psum[r] = s;
    }
    if (wc == 0 && r16 == 0) {
        #pragma unroll
        for (int r = 0; r < 4; r++)
            rs[wr * 16 + kg * 4 + r] = psum[r];
    }
    __syncthreads();
    if (wc == 1 && r16 == 0) {
        #pragma unroll
        for (int r = 0; r < 4; r++)
            rs[wr * 16 + kg * 4 + r] += psum[r];
    }
    __syncthreads();

    // ---- normalize + store y ----
    unsigned short* yB = yb + ((size_t)b * 4096 + q0) * 256;
    #pragma unroll
    for (int r = 0; r < 4; r++) {
        const int row = wr * 16 + kg * 4 + r;
        const float rinv = 1.0f / rs[row];
        #pragma unroll
        for (int ni = 0; ni < 8; ni++) {
            const int col = wc * 128 + ni * 16 + r16;
            yB[(size_t)row * 256 + col] = f2bf(yacc[ni][r] * rinv);
        }
    }
}

// 2x2 avgpool NHWC fp32 -> bf16, 4 channels per thread
__global__ __launch_bounds__(256)
void pool2(const float* __restrict__ x, unsigned short* __restrict__ xp)
{
    const int t  = blockIdx.x * 256 + threadIdx.x;   // 8*32*32*128 threads
    const int c4 = t & 127;
    const int j  = (t >> 7) & 31;
    const int i  = (t >> 12) & 31;
    const int b  = t >> 17;
    const float* p = x + ((((size_t)b * 64 + 2 * i) * 64) + 2 * j) * 512 + c4 * 4;
    vfloat4 a0 = *(const vfloat4*)p;
    vfloat4 a1 = *(const vfloat4*)(p + 512);
    vfloat4 a2 = *(const vfloat4*)(p + 64 * 512);
    vfloat4 a3 = *(const vfloat4*)(p + 64 * 512 + 512);
    float r0 = 0.25f * (a0[0] + a1[0] + a2[0] + a3[0]);
    float r1 = 0.25f * (a0[1] + a1[1] + a2[1] + a3[1]);
    float r2 = 0.25f * (a0[2] + a1[2] + a2[2] + a3[2]);
    float r3 = 0.25f * (a0[3] + a1[3] + a2[3] + a3[3]);
    vuint2 o;
    o[0] = (unsigned)f2bf(r0) | ((unsigned)f2bf(r1) << 16);
    o[1] = (unsigned)f2bf(r2) | ((unsigned)f2bf(r3) << 16);
    *(vuint2*)(xp + (size_t)t * 4) = o;
}

// weights: in fp32 [Kdim][Ndim] -> out bf16 [Ndim][Kdim]
__global__ __launch_bounds__(256)
void transpose_cast(const float* __restrict__ in, unsigned short* __restrict__ out,
                    int Kdim, int Ndim)
{
    const int idx = blockIdx.x * 256 + threadIdx.x;
    if (idx >= Kdim * Ndim) return;
    const int n = idx / Kdim, k = idx % Kdim;
    out[idx] = f2bf(in[(size_t)k * Ndim + n]);
}

// h [8][1024][256] bf16 -> ht [8][256][1024] bf16 (LDS 32x32 tiles)
__global__ __launch_bounds__(256)
void transpose_h(const unsigned short* __restrict__ h, unsigned short* __restrict__ ht)
{
    __shared__ unsigned short tile[32][33];
    const int b  = blockIdx.z;
    const int v0 = blockIdx.x * 32, m0 = blockIdx.y * 32;
    const int tx = threadIdx.x & 31, ty = threadIdx.x >> 5;  // ty 0..7
    const unsigned short* hp = h + (size_t)b * 1024 * 256;
    #pragma unroll
    for (int s = 0; s < 4; s++)
        tile[ty + s * 8][tx] = hp[(size_t)(m0 + ty + s * 8) * 256 + v0 + tx];
    __syncthreads();
    unsigned short* op = ht + (size_t)b * 256 * 1024;
    #pragma unroll
    for (int s = 0; s < 4; s++)
        op[(size_t)(v0 + ty + s * 8) * 1024 + m0 + tx] = tile[tx][ty + s * 8];
}

extern "C" void kernel_launch(void* const* d_in, const int* in_sizes, int n_in,
                              void* d_out, int out_size, void* d_ws, size_t ws_size,
                              hipStream_t stream)
{
    const float* x  = (const float*)d_in[0];
    const float* wf = (const float*)d_in[1];
    const float* wg = (const float*)d_in[2];
    const float* wh = (const float*)d_in[3];
    const float* wo = (const float*)d_in[4];
    float* out = (float*)d_out;

    char* ws = (char*)d_ws;
    size_t off = 0;
    auto carve = [&](size_t bytes) {
        char* p = ws + off;
        off = (off + bytes + 255) & ~(size_t)255;
        return p;
    };
    unsigned short* xp   = (unsigned short*)carve(8ll * 1024 * 512 * 2);   // pooled, bf16
    unsigned short* wf_t = (unsigned short*)carve(64 * 512 * 2);
    unsigned short* wg_t = (unsigned short*)carve(64 * 512 * 2);
    unsigned short* wh_t = (unsigned short*)carve(256 * 512 * 2);
    unsigned short* wo_t = (unsigned short*)carve(512 * 256 * 2);
    unsigned short* gb   = (unsigned short*)carve(8ll * 1024 * 64 * 2);    // keys
    unsigned short* hb   = (unsigned short*)carve(8ll * 1024 * 256 * 2);   // values
    unsigned short* ht   = (unsigned short*)carve(8ll * 256 * 1024 * 2);   // values^T
    unsigned short* yb   = (unsigned short*)carve(8ll * 4096 * 256 * 2);

    // weight prep (transpose + bf16 cast)
    transpose_cast<<<dim3(128),  256, 0, stream>>>(wf, wf_t, 512, 64);
    transpose_cast<<<dim3(128),  256, 0, stream>>>(wg, wg_t, 512, 64);
    transpose_cast<<<dim3(512),  256, 0, stream>>>(wh, wh_t, 512, 256);
    transpose_cast<<<dim3(512),  256, 0, stream>>>(wo, wo_t, 256, 512);

    // pooled map (bf16)
    pool2<<<dim3(4096), 256, 0, stream>>>(x, xp);

    // key/value projections from pooled map
    gemm_bt<1><<<dim3(1, 128, 1), 256, 0, stream>>>(xp, wg_t, gb, 8192, 64, 512);
    gemm_bt<1><<<dim3(4, 128, 1), 256, 0, stream>>>(xp, wh_t, hb, 8192, 256, 512);
    transpose_h<<<dim3(8, 32, 8), 256, 0, stream>>>(hb, ht);

    // fused f-projection + attention: y = softmax((x wf) g^T) h
    flash_attn<<<dim3(1024), 256, 0, stream>>>(x, wf_t, gb, ht, yb);

    // out = y @ wo  (fp32 store)
    gemm_bt<0><<<dim3(8, 512, 1), 256, 0, stream>>>(yb, wo_t, out, 32768, 512, 256);
}

// Round 5
// 213.319 us; speedup vs baseline: 1.4082x; 1.4082x over previous
//
#include <hip/hip_runtime.h>
#include <hip/hip_bf16.h>

typedef __attribute__((ext_vector_type(8))) short bshort8;      // 8 bf16 (4 VGPR) MFMA frag
typedef __attribute__((ext_vector_type(4))) float f32x4;        // MFMA accumulator
typedef __attribute__((ext_vector_type(4))) float vfloat4;
typedef __attribute__((ext_vector_type(4))) unsigned int vuint4;
typedef __attribute__((ext_vector_type(2))) unsigned int vuint2;

__device__ __forceinline__ unsigned short f2bf(float f) {
    union { float f; unsigned u; } v; v.f = f;
    unsigned u = v.u;
    u += 0x7fffu + ((u >> 16) & 1u);   // round-to-nearest-even
    return (unsigned short)(u >> 16);
}

// ---------------------------------------------------------------------------
// Generic batched C = A[M][K] @ Bt[N][K]^T (bf16), MFMA 16x16x32.
// Tile: BM=64, BN=64, BK=32; 4 waves 2x2. EPI: 0 = fp32 store, 1 = bf16 store
// ---------------------------------------------------------------------------
template<int EPI>
__global__ __launch_bounds__(256)
void gemm_bt(const unsigned short* __restrict__ Av, const unsigned short* __restrict__ Btv,
             void* __restrict__ Cv,
             int M, int N, int K,
             long long aB, long long bB, long long cB)
{
    __shared__ __align__(128) char sA[64 * 64];   // 64 rows x 32 bf16 (64B/row)
    __shared__ __align__(128) char sB[64 * 64];

    const int b    = blockIdx.z;
    const int tid  = threadIdx.x;
    const int bRow = blockIdx.y << 6;
    const int bCol = blockIdx.x << 6;
    const int wid  = tid >> 6, lane = tid & 63;
    const int wr   = wid >> 1, wc   = wid & 1;
    const int r16  = lane & 15, kg  = lane >> 4;
    const int srow = tid >> 2,  skc = tid & 3;     // staging: row 0..63, k-chunk 0..3

    const unsigned short* A  = Av  + (size_t)aB * b;
    const unsigned short* Bt = Btv + (size_t)bB * b;

    f32x4 acc[2][2] = {};

    const size_t aRowBase = (size_t)(bRow + srow) * K + skc * 8;
    const size_t bRowBase = (size_t)(bCol + srow) * K + skc * 8;
    const unsigned swW = ((((unsigned)srow) << 6) | (((unsigned)skc) << 4))
                         ^ ((((unsigned)srow) & 7u) << 4);

    for (int k0 = 0; k0 < K; k0 += 32) {
        vuint4 apack = *(const vuint4*)(A  + aRowBase + k0);
        vuint4 bpack = *(const vuint4*)(Bt + bRowBase + k0);
        *(vuint4*)(sA + swW) = apack;
        *(vuint4*)(sB + swW) = bpack;
        __syncthreads();

        bshort8 af[2], bfr[2];
        #pragma unroll
        for (int mi = 0; mi < 2; mi++) {
            unsigned row = (unsigned)(wr * 32 + mi * 16 + r16);
            unsigned off = ((row << 6) | (((unsigned)kg) << 4)) ^ ((row & 7u) << 4);
            af[mi] = *(const bshort8*)(sA + off);
        }
        #pragma unroll
        for (int ni = 0; ni < 2; ni++) {
            unsigned col = (unsigned)(wc * 32 + ni * 16 + r16);
            unsigned off = ((col << 6) | (((unsigned)kg) << 4)) ^ ((col & 7u) << 4);
            bfr[ni] = *(const bshort8*)(sB + off);
        }
        #pragma unroll
        for (int mi = 0; mi < 2; mi++)
            #pragma unroll
            for (int ni = 0; ni < 2; ni++)
                acc[mi][ni] = __builtin_amdgcn_mfma_f32_16x16x32_bf16(
                                  af[mi], bfr[ni], acc[mi][ni], 0, 0, 0);
        __syncthreads();
    }

    // D frag: col = lane&15, row = (lane>>4)*4 + r  [verified layout]
    #pragma unroll
    for (int mi = 0; mi < 2; mi++) {
        const int row0 = bRow + wr * 32 + mi * 16 + kg * 4;
        #pragma unroll
        for (int ni = 0; ni < 2; ni++) {
            const int col = bCol + wc * 32 + ni * 16 + r16;
            #pragma unroll
            for (int r = 0; r < 4; r++) {
                const int row = row0 + r;
                float x = acc[mi][ni][r];
                const size_t ci = (size_t)cB * b + (size_t)row * N + col;
                if constexpr (EPI == 0) ((float*)Cv)[ci] = x;
                else                    ((unsigned short*)Cv)[ci] = f2bf(x);
            }
        }
    }
}

// ---------------------------------------------------------------------------
// Flash attention v3: Q-tile=128, 512 threads (8 waves), f-projection fused.
//   f = x @ wf (K=512), S = f @ g^T (K=64), P = exp(S), y = (P@h)/rowsum(P)
// Wave (wr=wid>>1, wc=wid&1): QK tile 32q x 32k, PV tile 32q x 128n.
// f-phase: each wave computes 16 f-rows x 64 cols.
// Grid: flat 256 (= #CUs); batch = bid&7. LDS 56.5KB, 1 block/CU, 8 waves/CU.
// Per KV chunk: 320 MFMA vs 40KB staged (2x v1, 4x v2 compute density).
// ---------------------------------------------------------------------------
__global__ __launch_bounds__(512)
void flash_attn(const float* __restrict__ x,
                const unsigned short* __restrict__ wft,
                const unsigned short* __restrict__ gb,
                const unsigned short* __restrict__ ht,
                unsigned short* __restrict__ yb)
{
    __shared__ __align__(128) char sS[128 * 128];   // f tile / P tile (16KB)
    __shared__ __align__(128) char sG[64 * 128];    // wf chunk / g chunk (8KB)
    __shared__ __align__(128) char sH[256 * 128];   // x chunk / ht chunk (32KB)
    __shared__ float rs[128];

    const int tid = threadIdx.x;
    const int bid = blockIdx.x;
    const int b   = bid & 7;            // batch == XCD slot (L2-local KV)
    const int q0  = (bid >> 3) << 7;    // 128 q-rows per block
    const int wid = tid >> 6, lane = tid & 63;
    const int wr  = wid >> 1, wc = wid & 1;
    const int r16 = lane & 15, kg = lane >> 4;

    const float*          xB = x  + ((size_t)b * 4096 + q0) * 512;
    const unsigned short* gB = gb + (size_t)b * 1024 * 64;
    const unsigned short* hB = ht + (size_t)b * 256 * 1024;

    // ================= f = x @ wf  (128 x 64, K=512, BK=64) =================
    f32x4 facc[4] = {};
    {
        const int xrow = tid >> 2, xc = tid & 3;     // x: 128 rows, 4 thr/row
        const int wrow = tid >> 3, wkc = tid & 7;    // wf: 64 rows, 8 thr/row
        const int frow = wid << 4;                   // wave's 16 f-rows
        for (int k0 = 0; k0 < 512; k0 += 64) {
            {   // stage x chunk [128][64] -> sH (bf16, swizzled): 2 vuint4/thread
                const float* p = xB + (size_t)xrow * 512 + k0 + xc * 16;
                #pragma unroll
                for (int j = 0; j < 2; j++) {
                    vfloat4 a0 = *(const vfloat4*)(p + j * 8);
                    vfloat4 a1 = *(const vfloat4*)(p + j * 8 + 4);
                    vuint4 w;
                    w[0] = (unsigned)f2bf(a0[0]) | ((unsigned)f2bf(a0[1]) << 16);
                    w[1] = (unsigned)f2bf(a0[2]) | ((unsigned)f2bf(a0[3]) << 16);
                    w[2] = (unsigned)f2bf(a1[0]) | ((unsigned)f2bf(a1[1]) << 16);
                    w[3] = (unsigned)f2bf(a1[2]) | ((unsigned)f2bf(a1[3]) << 16);
                    unsigned off = ((unsigned)xrow * 128 + (unsigned)(xc * 32 + j * 16))
                                   ^ (((unsigned)xrow & 7u) << 4);
                    *(vuint4*)(sH + off) = w;
                }
            }
            {   // stage wf chunk [64][64] -> sG: 1 vuint4/thread
                vuint4 v = *(const vuint4*)(wft + (size_t)wrow * 512 + k0 + wkc * 8);
                unsigned off = ((unsigned)wrow * 128 + (unsigned)wkc * 16)
                               ^ (((unsigned)wrow & 7u) << 4);
                *(vuint4*)(sG + off) = v;
            }
            __syncthreads();

            bshort8 ax[2];
            {
                unsigned row = (unsigned)(frow + r16);
                unsigned base = row * 128, sw = (row & 7u) << 4;
                ax[0] = *(const bshort8*)(sH + ((base + (unsigned)kg * 16) ^ sw));
                ax[1] = *(const bshort8*)(sH + ((base + 64 + (unsigned)kg * 16) ^ sw));
            }
            #pragma unroll
            for (int ni = 0; ni < 4; ni++) {
                unsigned col = (unsigned)(ni * 16 + r16);
                unsigned base = col * 128, sw = (col & 7u) << 4;
                bshort8 b0 = *(const bshort8*)(sG + ((base + (unsigned)kg * 16) ^ sw));
                bshort8 b1 = *(const bshort8*)(sG + ((base + 64 + (unsigned)kg * 16) ^ sw));
                facc[ni] = __builtin_amdgcn_mfma_f32_16x16x32_bf16(ax[0], b0, facc[ni], 0, 0, 0);
                facc[ni] = __builtin_amdgcn_mfma_f32_16x16x32_bf16(ax[1], b1, facc[ni], 0, 0, 0);
            }
            __syncthreads();
        }

        // redistribute f: C-layout acc -> sS (bf16, swizzled)
        #pragma unroll
        for (int ni = 0; ni < 4; ni++) {
            const unsigned col = (unsigned)(ni * 16 + r16);
            #pragma unroll
            for (int r = 0; r < 4; r++) {
                unsigned row = (unsigned)(frow + kg * 4 + r);
                unsigned off = (row * 128 + col * 2) ^ ((row & 7u) << 4);
                *(unsigned short*)(sS + off) = f2bf(facc[ni][r]);
            }
        }
    }
    __syncthreads();

    // A-frags of f for QK, held in registers
    bshort8 af[2][2];
    #pragma unroll
    for (int mi = 0; mi < 2; mi++) {
        unsigned row = (unsigned)(wr * 32 + mi * 16 + r16);
        unsigned base = row * 128, sw = (row & 7u) << 4;
        af[mi][0] = *(const bshort8*)(sS + ((base + (unsigned)kg * 16) ^ sw));
        af[mi][1] = *(const bshort8*)(sS + ((base + 64 + (unsigned)kg * 16) ^ sw));
    }

    // ================= KV loop =================
    f32x4 yacc[2][8] = {};
    float psum[2][4] = {};
    const int kc = tid & 7, n0 = tid >> 3;   // staging: 64 rows, 8 thr/row

    for (int c = 0; c < 16; c++) {
        const int kv0 = c << 6;
        {   // stage g chunk [64 keys][64 d]: 1 vuint4/thread
            vuint4 v = *(const vuint4*)(gB + (size_t)(kv0 + n0) * 64 + kc * 8);
            unsigned off = ((unsigned)n0 * 128 + (unsigned)kc * 16) ^ (((unsigned)n0 & 7u) << 4);
            *(vuint4*)(sG + off) = v;
        }
        #pragma unroll
        for (int it = 0; it < 4; it++) {   // stage ht chunk [256 n][64 k]: 4/thread
            const int n = n0 + it * 64;
            vuint4 v = *(const vuint4*)(hB + (size_t)n * 1024 + kv0 + kc * 8);
            unsigned off = ((unsigned)n * 128 + (unsigned)kc * 16) ^ (((unsigned)n & 7u) << 4);
            *(vuint4*)(sH + off) = v;
        }
        __syncthreads();

        // ---- QK: S = f @ g^T ----
        f32x4 sacc[2][2] = {};
        #pragma unroll
        for (int ni = 0; ni < 2; ni++) {
            unsigned col = (unsigned)(wc * 32 + ni * 16 + r16);
            unsigned base = col * 128, sw = (col & 7u) << 4;
            bshort8 g0 = *(const bshort8*)(sG + ((base + (unsigned)kg * 16) ^ sw));
            bshort8 g1 = *(const bshort8*)(sG + ((base + 64 + (unsigned)kg * 16) ^ sw));
            #pragma unroll
            for (int mi = 0; mi < 2; mi++) {
                sacc[mi][ni] = __builtin_amdgcn_mfma_f32_16x16x32_bf16(af[mi][0], g0, sacc[mi][ni], 0, 0, 0);
                sacc[mi][ni] = __builtin_amdgcn_mfma_f32_16x16x32_bf16(af[mi][1], g1, sacc[mi][ni], 0, 0, 0);
            }
        }

        // ---- exp, rowsum partials, write P tile to sS ----
        #pragma unroll
        for (int mi = 0; mi < 2; mi++)
            #pragma unroll
            for (int ni = 0; ni < 2; ni++) {
                const unsigned col = (unsigned)(wc * 32 + ni * 16 + r16);
                #pragma unroll
                for (int r = 0; r < 4; r++) {
                    float e = __expf(sacc[mi][ni][r]);
                    psum[mi][r] += e;
                    unsigned row = (unsigned)(wr * 32 + mi * 16 + kg * 4 + r);
                    unsigned off = (row * 128 + col * 2) ^ ((row & 7u) << 4);
                    *(unsigned short*)(sS + off) = f2bf(e);
                }
            }
        __syncthreads();

        // ---- PV: yacc += P @ h ----
        bshort8 pa[2][2];
        #pragma unroll
        for (int mi = 0; mi < 2; mi++) {
            unsigned row = (unsigned)(wr * 32 + mi * 16 + r16);
            unsigned base = row * 128, sw = (row & 7u) << 4;
            pa[mi][0] = *(const bshort8*)(sS + ((base + (unsigned)kg * 16) ^ sw));
            pa[mi][1] = *(const bshort8*)(sS + ((base + 64 + (unsigned)kg * 16) ^ sw));
        }
        #pragma unroll
        for (int ni = 0; ni < 8; ni++) {
            unsigned col = (unsigned)(wc * 128 + ni * 16 + r16);
            unsigned base = col * 128, sw = (col & 7u) << 4;
            bshort8 b0 = *(const bshort8*)(sH + ((base + (unsigned)kg * 16) ^ sw));
            bshort8 b1 = *(const bshort8*)(sH + ((base + 64 + (unsigned)kg * 16) ^ sw));
            #pragma unroll
            for (int mi = 0; mi < 2; mi++) {
                yacc[mi][ni] = __builtin_amdgcn_mfma_f32_16x16x32_bf16(pa[mi][0], b0, yacc[mi][ni], 0, 0, 0);
                yacc[mi][ni] = __builtin_amdgcn_mfma_f32_16x16x32_bf16(pa[mi][1], b1, yacc[mi][ni], 0, 0, 0);
            }
        }
        __syncthreads();
    }

    // ---- rowsum: reduce over 16 key-lanes, then combine wc pairs via LDS ----
    #pragma unroll
    for (int mi = 0; mi < 2; mi++)
        #pragma unroll
        for (int r = 0; r < 4; r++) {
            float s = psum[mi][r];
            s += __shfl_xor(s, 1, 64);
            s += __shfl_xor(s, 2, 64);
            s += __shfl_xor(s, 4, 64);
            s += __shfl_xor(s, 8, 64);
            psum[mi][r] = s;
        }
    if (wc == 0 && r16 == 0) {
        #pragma unroll
        for (int mi = 0; mi < 2; mi++)
            #pragma unroll
            for (int r = 0; r < 4; r++)
                rs[wr * 32 + mi * 16 + kg * 4 + r] = psum[mi][r];
    }
    __syncthreads();
    if (wc == 1 && r16 == 0) {
        #pragma unroll
        for (int mi = 0; mi < 2; mi++)
            #pragma unroll
            for (int r = 0; r < 4; r++)
                rs[wr * 32 + mi * 16 + kg * 4 + r] += psum[mi][r];
    }
    __syncthreads();

    // ---- normalize + store y ----
    unsigned short* yB = yb + ((size_t)b * 4096 + q0) * 256;
    #pragma unroll
    for (int mi = 0; mi < 2; mi++)
        #pragma unroll
        for (int r = 0; r < 4; r++) {
            const int row = wr * 32 + mi * 16 + kg * 4 + r;
            const float rinv = 1.0f / rs[row];
            #pragma unroll
            for (int ni = 0; ni < 8; ni++) {
                const int col = wc * 128 + ni * 16 + r16;
                yB[(size_t)row * 256 + col] = f2bf(yacc[mi][ni][r] * rinv);
            }
        }
}

// 2x2 avgpool NHWC fp32 -> bf16, 4 channels per thread
__global__ __launch_bounds__(256)
void pool2(const float* __restrict__ x, unsigned short* __restrict__ xp)
{
    const int t  = blockIdx.x * 256 + threadIdx.x;   // 8*32*32*128 threads
    const int c4 = t & 127;
    const int j  = (t >> 7) & 31;
    const int i  = (t >> 12) & 31;
    const int b  = t >> 17;
    const float* p = x + ((((size_t)b * 64 + 2 * i) * 64) + 2 * j) * 512 + c4 * 4;
    vfloat4 a0 = *(const vfloat4*)p;
    vfloat4 a1 = *(const vfloat4*)(p + 512);
    vfloat4 a2 = *(const vfloat4*)(p + 64 * 512);
    vfloat4 a3 = *(const vfloat4*)(p + 64 * 512 + 512);
    float r0 = 0.25f * (a0[0] + a1[0] + a2[0] + a3[0]);
    float r1 = 0.25f * (a0[1] + a1[1] + a2[1] + a3[1]);
    float r2 = 0.25f * (a0[2] + a1[2] + a2[2] + a3[2]);
    float r3 = 0.25f * (a0[3] + a1[3] + a2[3] + a3[3]);
    vuint2 o;
    o[0] = (unsigned)f2bf(r0) | ((unsigned)f2bf(r1) << 16);
    o[1] = (unsigned)f2bf(r2) | ((unsigned)f2bf(r3) << 16);
    *(vuint2*)(xp + (size_t)t * 4) = o;
}

// weights: in fp32 [Kdim][Ndim] -> out bf16 [Ndim][Kdim]
__global__ __launch_bounds__(256)
void transpose_cast(const float* __restrict__ in, unsigned short* __restrict__ out,
                    int Kdim, int Ndim)
{
    const int idx = blockIdx.x * 256 + threadIdx.x;
    if (idx >= Kdim * Ndim) return;
    const int n = idx / Kdim, k = idx % Kdim;
    out[idx] = f2bf(in[(size_t)k * Ndim + n]);
}

extern "C" void kernel_launch(void* const* d_in, const int* in_sizes, int n_in,
                              void* d_out, int out_size, void* d_ws, size_t ws_size,
                              hipStream_t stream)
{
    const float* x  = (const float*)d_in[0];
    const float* wf = (const float*)d_in[1];
    const float* wg = (const float*)d_in[2];
    const float* wh = (const float*)d_in[3];
    const float* wo = (const float*)d_in[4];
    float* out = (float*)d_out;

    char* ws = (char*)d_ws;
    size_t off = 0;
    auto carve = [&](size_t bytes) {
        char* p = ws + off;
        off = (off + bytes + 255) & ~(size_t)255;
        return p;
    };
    unsigned short* xp   = (unsigned short*)carve(8ll * 1024 * 512 * 2);   // pooled, bf16
    unsigned short* wf_t = (unsigned short*)carve(64 * 512 * 2);
    unsigned short* wg_t = (unsigned short*)carve(64 * 512 * 2);
    unsigned short* wh_t = (unsigned short*)carve(256 * 512 * 2);
    unsigned short* wo_t = (unsigned short*)carve(512 * 256 * 2);
    unsigned short* gb   = (unsigned short*)carve(8ll * 1024 * 64 * 2);    // keys
    unsigned short* ht   = (unsigned short*)carve(8ll * 256 * 1024 * 2);   // values^T
    unsigned short* yb   = (unsigned short*)carve(8ll * 4096 * 256 * 2);

    // weight prep (transpose + bf16 cast)
    transpose_cast<<<dim3(128),  256, 0, stream>>>(wf, wf_t, 512, 64);
    transpose_cast<<<dim3(128),  256, 0, stream>>>(wg, wg_t, 512, 64);
    transpose_cast<<<dim3(512),  256, 0, stream>>>(wh, wh_t, 512, 256);
    transpose_cast<<<dim3(512),  256, 0, stream>>>(wo, wo_t, 256, 512);

    // pooled map (bf16)
    pool2<<<dim3(4096), 256, 0, stream>>>(x, xp);

    // g = xp @ wg   (flattened over batches)
    gemm_bt<1><<<dim3(1, 128, 1), 256, 0, stream>>>(xp, wg_t, gb, 8192, 64, 512, 0, 0, 0);
    // ht_b = wh^T @ xp_b^T  == (xp_b @ wh)^T  directly (no separate transpose)
    gemm_bt<1><<<dim3(16, 4, 8), 256, 0, stream>>>(wh_t, xp, ht, 256, 1024, 512,
                                                   0, 1024LL * 512, 256LL * 1024);

    // fused f-projection + attention: y = softmax((x wf) g^T) h
    flash_attn<<<dim3(256), 512, 0, stream>>>(x, wf_t, gb, ht, yb);

    // out = y @ wo  (fp32 store)
    gemm_bt<0><<<dim3(8, 512, 1), 256, 0, stream>>>(yb, wo_t, out, 32768, 512, 256, 0, 0, 0);
}

// Round 6
// 203.319 us; speedup vs baseline: 1.4775x; 1.0492x over previous
//
#include <hip/hip_runtime.h>
#include <hip/hip_bf16.h>

typedef __attribute__((ext_vector_type(8))) short bshort8;      // 8 bf16 (4 VGPR) MFMA frag
typedef __attribute__((ext_vector_type(4))) float f32x4;        // MFMA accumulator
typedef __attribute__((ext_vector_type(4))) float vfloat4;
typedef __attribute__((ext_vector_type(4))) unsigned int vuint4;
typedef __attribute__((ext_vector_type(2))) unsigned int vuint2;

__device__ __forceinline__ unsigned short f2bf(float f) {
    union { float f; unsigned u; } v; v.f = f;
    unsigned u = v.u;
    u += 0x7fffu + ((u >> 16) & 1u);   // round-to-nearest-even
    return (unsigned short)(u >> 16);
}

// ---------------------------------------------------------------------------
// Generic batched C = A[M][K] @ Bt[N][K]^T (bf16), MFMA 16x16x32.
// Tile: BM=64, BN=64, BK=32; 4 waves 2x2. EPI: 0 = fp32 store, 1 = bf16 store
// ---------------------------------------------------------------------------
template<int EPI>
__global__ __launch_bounds__(256)
void gemm_bt(const unsigned short* __restrict__ Av, const unsigned short* __restrict__ Btv,
             void* __restrict__ Cv,
             int M, int N, int K,
             long long aB, long long bB, long long cB)
{
    __shared__ __align__(128) char sA[64 * 64];   // 64 rows x 32 bf16 (64B/row)
    __shared__ __align__(128) char sB[64 * 64];

    const int b    = blockIdx.z;
    const int tid  = threadIdx.x;
    const int bRow = blockIdx.y << 6;
    const int bCol = blockIdx.x << 6;
    const int wid  = tid >> 6, lane = tid & 63;
    const int wr   = wid >> 1, wc   = wid & 1;
    const int r16  = lane & 15, kg  = lane >> 4;
    const int srow = tid >> 2,  skc = tid & 3;     // staging: row 0..63, k-chunk 0..3

    const unsigned short* A  = Av  + (size_t)aB * b;
    const unsigned short* Bt = Btv + (size_t)bB * b;

    f32x4 acc[2][2] = {};

    const size_t aRowBase = (size_t)(bRow + srow) * K + skc * 8;
    const size_t bRowBase = (size_t)(bCol + srow) * K + skc * 8;
    const unsigned swW = ((((unsigned)srow) << 6) | (((unsigned)skc) << 4))
                         ^ ((((unsigned)srow) & 7u) << 4);

    for (int k0 = 0; k0 < K; k0 += 32) {
        vuint4 apack = *(const vuint4*)(A  + aRowBase + k0);
        vuint4 bpack = *(const vuint4*)(Bt + bRowBase + k0);
        *(vuint4*)(sA + swW) = apack;
        *(vuint4*)(sB + swW) = bpack;
        __syncthreads();

        bshort8 af[2], bfr[2];
        #pragma unroll
        for (int mi = 0; mi < 2; mi++) {
            unsigned row = (unsigned)(wr * 32 + mi * 16 + r16);
            unsigned off = ((row << 6) | (((unsigned)kg) << 4)) ^ ((row & 7u) << 4);
            af[mi] = *(const bshort8*)(sA + off);
        }
        #pragma unroll
        for (int ni = 0; ni < 2; ni++) {
            unsigned col = (unsigned)(wc * 32 + ni * 16 + r16);
            unsigned off = ((col << 6) | (((unsigned)kg) << 4)) ^ ((col & 7u) << 4);
            bfr[ni] = *(const bshort8*)(sB + off);
        }
        #pragma unroll
        for (int mi = 0; mi < 2; mi++)
            #pragma unroll
            for (int ni = 0; ni < 2; ni++)
                acc[mi][ni] = __builtin_amdgcn_mfma_f32_16x16x32_bf16(
                                  af[mi], bfr[ni], acc[mi][ni], 0, 0, 0);
        __syncthreads();
    }

    // D frag: col = lane&15, row = (lane>>4)*4 + r  [verified layout]
    #pragma unroll
    for (int mi = 0; mi < 2; mi++) {
        const int row0 = bRow + wr * 32 + mi * 16 + kg * 4;
        #pragma unroll
        for (int ni = 0; ni < 2; ni++) {
            const int col = bCol + wc * 32 + ni * 16 + r16;
            #pragma unroll
            for (int r = 0; r < 4; r++) {
                const int row = row0 + r;
                float x = acc[mi][ni][r];
                const size_t ci = (size_t)cB * b + (size_t)row * N + col;
                if constexpr (EPI == 0) ((float*)Cv)[ci] = x;
                else                    ((unsigned short*)Cv)[ci] = f2bf(x);
            }
        }
    }
}

// ---------------------------------------------------------------------------
// Flash attention v4: Q-tile=128, 512 threads, f-projection fused,
// DOUBLE-BUFFERED KV staging with issue-early/write-late (T14 split):
// chunk c+1 global loads fly under chunk c's QK+exp+PV; ds_writes land
// after PV into the inactive buffer. LDS 96.5KB, 1 block/CU.
// ---------------------------------------------------------------------------
__global__ __launch_bounds__(512)
void flash_attn(const float* __restrict__ x,
                const unsigned short* __restrict__ wft,
                const unsigned short* __restrict__ gb,
                const unsigned short* __restrict__ ht,
                unsigned short* __restrict__ yb)
{
    __shared__ __align__(128) char sS[128 * 128];       // f tile / P tile (16KB)
    __shared__ __align__(128) char sG[2][64 * 128];     // g dbuf (16KB)
    __shared__ __align__(128) char sH[2][256 * 128];    // ht dbuf (64KB)
    __shared__ float rs[128];

    const int tid = threadIdx.x;
    const int bid = blockIdx.x;
    const int b   = bid & 7;            // batch == XCD slot (L2-local KV)
    const int q0  = (bid >> 3) << 7;    // 128 q-rows per block
    const int wid = tid >> 6, lane = tid & 63;
    const int wr  = wid >> 1, wc = wid & 1;
    const int r16 = lane & 15, kg = lane >> 4;

    const float*          xB = x  + ((size_t)b * 4096 + q0) * 512;
    const unsigned short* gB = gb + (size_t)b * 1024 * 64;
    const unsigned short* hB = ht + (size_t)b * 256 * 1024;

    char* const sG0 = sG[0];
    char* const sH0 = sH[0];

    // ================= f = x @ wf  (128 x 64, K=512, BK=64) =================
    f32x4 facc[4] = {};
    {
        const int xrow = tid >> 2, xc = tid & 3;     // x: 128 rows, 4 thr/row
        const int wrow = tid >> 3, wkc = tid & 7;    // wf: 64 rows, 8 thr/row
        const int frow = wid << 4;                   // wave's 16 f-rows
        for (int k0 = 0; k0 < 512; k0 += 64) {
            {   // stage x chunk [128][64] -> sH0 (bf16, swizzled): 2 vuint4/thread
                const float* p = xB + (size_t)xrow * 512 + k0 + xc * 16;
                #pragma unroll
                for (int j = 0; j < 2; j++) {
                    vfloat4 a0 = *(const vfloat4*)(p + j * 8);
                    vfloat4 a1 = *(const vfloat4*)(p + j * 8 + 4);
                    vuint4 w;
                    w[0] = (unsigned)f2bf(a0[0]) | ((unsigned)f2bf(a0[1]) << 16);
                    w[1] = (unsigned)f2bf(a0[2]) | ((unsigned)f2bf(a0[3]) << 16);
                    w[2] = (unsigned)f2bf(a1[0]) | ((unsigned)f2bf(a1[1]) << 16);
                    w[3] = (unsigned)f2bf(a1[2]) | ((unsigned)f2bf(a1[3]) << 16);
                    unsigned off = ((unsigned)xrow * 128 + (unsigned)(xc * 32 + j * 16))
                                   ^ (((unsigned)xrow & 7u) << 4);
                    *(vuint4*)(sH0 + off) = w;
                }
            }
            {   // stage wf chunk [64][64] -> sG0: 1 vuint4/thread
                vuint4 v = *(const vuint4*)(wft + (size_t)wrow * 512 + k0 + wkc * 8);
                unsigned off = ((unsigned)wrow * 128 + (unsigned)wkc * 16)
                               ^ (((unsigned)wrow & 7u) << 4);
                *(vuint4*)(sG0 + off) = v;
            }
            __syncthreads();

            bshort8 ax[2];
            {
                unsigned row = (unsigned)(frow + r16);
                unsigned base = row * 128, sw = (row & 7u) << 4;
                ax[0] = *(const bshort8*)(sH0 + ((base + (unsigned)kg * 16) ^ sw));
                ax[1] = *(const bshort8*)(sH0 + ((base + 64 + (unsigned)kg * 16) ^ sw));
            }
            #pragma unroll
            for (int ni = 0; ni < 4; ni++) {
                unsigned col = (unsigned)(ni * 16 + r16);
                unsigned base = col * 128, sw = (col & 7u) << 4;
                bshort8 b0 = *(const bshort8*)(sG0 + ((base + (unsigned)kg * 16) ^ sw));
                bshort8 b1 = *(const bshort8*)(sG0 + ((base + 64 + (unsigned)kg * 16) ^ sw));
                facc[ni] = __builtin_amdgcn_mfma_f32_16x16x32_bf16(ax[0], b0, facc[ni], 0, 0, 0);
                facc[ni] = __builtin_amdgcn_mfma_f32_16x16x32_bf16(ax[1], b1, facc[ni], 0, 0, 0);
            }
            __syncthreads();
        }

        // redistribute f: C-layout acc -> sS (bf16, swizzled)
        const int frow2 = wid << 4;
        #pragma unroll
        for (int ni = 0; ni < 4; ni++) {
            const unsigned col = (unsigned)(ni * 16 + r16);
            #pragma unroll
            for (int r = 0; r < 4; r++) {
                unsigned row = (unsigned)(frow2 + kg * 4 + r);
                unsigned off = (row * 128 + col * 2) ^ ((row & 7u) << 4);
                *(unsigned short*)(sS + off) = f2bf(facc[ni][r]);
            }
        }
    }

    // ================= prologue: stage chunk 0 into buf 0 =================
    const int kc = tid & 7, n0 = tid >> 3;           // staging: 64 rows, 8 thr/row
    const unsigned gOff  = ((unsigned)n0 * 128 + (unsigned)kc * 16) ^ (((unsigned)n0 & 7u) << 4);
    const unsigned hOff0 = gOff;                      // (n0+64k)&7 == n0&7 -> +k*8192

    vuint4 gR, hR0, hR1, hR2, hR3;
    gR  = *(const vuint4*)(gB + (size_t)n0 * 64 + kc * 8);
    hR0 = *(const vuint4*)(hB + (size_t)(n0      ) * 1024 + kc * 8);
    hR1 = *(const vuint4*)(hB + (size_t)(n0 +  64) * 1024 + kc * 8);
    hR2 = *(const vuint4*)(hB + (size_t)(n0 + 128) * 1024 + kc * 8);
    hR3 = *(const vuint4*)(hB + (size_t)(n0 + 192) * 1024 + kc * 8);
    // safe: f-loop's trailing barrier means all waves finished reading sG0/sH0
    *(vuint4*)(sG0 + gOff)               = gR;
    *(vuint4*)(sH0 + hOff0)              = hR0;
    *(vuint4*)(sH0 + hOff0 +     8192)   = hR1;
    *(vuint4*)(sH0 + hOff0 + 2 * 8192)   = hR2;
    *(vuint4*)(sH0 + hOff0 + 3 * 8192)   = hR3;
    __syncthreads();                      // buf0 + sS(f) visible

    // A-frags of f for QK, held in registers
    bshort8 af[2][2];
    #pragma unroll
    for (int mi = 0; mi < 2; mi++) {
        unsigned row = (unsigned)(wr * 32 + mi * 16 + r16);
        unsigned base = row * 128, sw = (row & 7u) << 4;
        af[mi][0] = *(const bshort8*)(sS + ((base + (unsigned)kg * 16) ^ sw));
        af[mi][1] = *(const bshort8*)(sS + ((base + 64 + (unsigned)kg * 16) ^ sw));
    }
    __syncthreads();                      // af reads done before c=0 P-writes

    // ================= KV loop (double-buffered) =================
    f32x4 yacc[2][8] = {};
    float psum[2][4] = {};

    for (int c = 0; c < 16; c++) {
        const int cur = c & 1;
        char* const sGc = sG[cur];
        char* const sHc = sH[cur];

        // issue chunk c+1 loads early — fly under QK+exp+PV
        if (c < 15) {
            const int kv1 = (c + 1) << 6;
            gR  = *(const vuint4*)(gB + (size_t)(kv1 + n0) * 64 + kc * 8);
            hR0 = *(const vuint4*)(hB + (size_t)(n0      ) * 1024 + kv1 + kc * 8);
            hR1 = *(const vuint4*)(hB + (size_t)(n0 +  64) * 1024 + kv1 + kc * 8);
            hR2 = *(const vuint4*)(hB + (size_t)(n0 + 128) * 1024 + kv1 + kc * 8);
            hR3 = *(const vuint4*)(hB + (size_t)(n0 + 192) * 1024 + kv1 + kc * 8);
        }

        // ---- QK: S = f @ g^T ----
        f32x4 sacc[2][2] = {};
        #pragma unroll
        for (int ni = 0; ni < 2; ni++) {
            unsigned col = (unsigned)(wc * 32 + ni * 16 + r16);
            unsigned base = col * 128, sw = (col & 7u) << 4;
            bshort8 g0 = *(const bshort8*)(sGc + ((base + (unsigned)kg * 16) ^ sw));
            bshort8 g1 = *(const bshort8*)(sGc + ((base + 64 + (unsigned)kg * 16) ^ sw));
            #pragma unroll
            for (int mi = 0; mi < 2; mi++) {
                sacc[mi][ni] = __builtin_amdgcn_mfma_f32_16x16x32_bf16(af[mi][0], g0, sacc[mi][ni], 0, 0, 0);
                sacc[mi][ni] = __builtin_amdgcn_mfma_f32_16x16x32_bf16(af[mi][1], g1, sacc[mi][ni], 0, 0, 0);
            }
        }

        // ---- exp, rowsum partials, write P tile to sS ----
        #pragma unroll
        for (int mi = 0; mi < 2; mi++)
            #pragma unroll
            for (int ni = 0; ni < 2; ni++) {
                const unsigned col = (unsigned)(wc * 32 + ni * 16 + r16);
                #pragma unroll
                for (int r = 0; r < 4; r++) {
                    float e = __expf(sacc[mi][ni][r]);
                    psum[mi][r] += e;
                    unsigned row = (unsigned)(wr * 32 + mi * 16 + kg * 4 + r);
                    unsigned off = (row * 128 + col * 2) ^ ((row & 7u) << 4);
                    *(unsigned short*)(sS + off) = f2bf(e);
                }
            }
        __syncthreads();

        // ---- PV: yacc += P @ h ----
        bshort8 pa[2][2];
        #pragma unroll
        for (int mi = 0; mi < 2; mi++) {
            unsigned row = (unsigned)(wr * 32 + mi * 16 + r16);
            unsigned base = row * 128, sw = (row & 7u) << 4;
            pa[mi][0] = *(const bshort8*)(sS + ((base + (unsigned)kg * 16) ^ sw));
            pa[mi][1] = *(const bshort8*)(sS + ((base + 64 + (unsigned)kg * 16) ^ sw));
        }
        #pragma unroll
        for (int ni = 0; ni < 8; ni++) {
            unsigned col = (unsigned)(wc * 128 + ni * 16 + r16);
            unsigned base = col * 128, sw = (col & 7u) << 4;
            bshort8 b0 = *(const bshort8*)(sHc + ((base + (unsigned)kg * 16) ^ sw));
            bshort8 b1 = *(const bshort8*)(sHc + ((base + 64 + (unsigned)kg * 16) ^ sw));
            #pragma unroll
            for (int mi = 0; mi < 2; mi++) {
                yacc[mi][ni] = __builtin_amdgcn_mfma_f32_16x16x32_bf16(pa[mi][0], b0, yacc[mi][ni], 0, 0, 0);
                yacc[mi][ni] = __builtin_amdgcn_mfma_f32_16x16x32_bf16(pa[mi][1], b1, yacc[mi][ni], 0, 0, 0);
            }
        }

        // write chunk c+1 into the inactive buffer
        if (c < 15) {
            char* const sGn = sG[cur ^ 1];
            char* const sHn = sH[cur ^ 1];
            *(vuint4*)(sGn + gOff)             = gR;
            *(vuint4*)(sHn + hOff0)            = hR0;
            *(vuint4*)(sHn + hOff0 +     8192) = hR1;
            *(vuint4*)(sHn + hOff0 + 2 * 8192) = hR2;
            *(vuint4*)(sHn + hOff0 + 3 * 8192) = hR3;
        }
        __syncthreads();   // PV reads of sHc done + next buffer visible
    }

    // ---- rowsum: reduce over 16 key-lanes, then combine wc pairs via LDS ----
    #pragma unroll
    for (int mi = 0; mi < 2; mi++)
        #pragma unroll
        for (int r = 0; r < 4; r++) {
            float s = psum[mi][r];
            s += __shfl_xor(s, 1, 64);
            s += __shfl_xor(s, 2, 64);
            s += __shfl_xor(s, 4, 64);
            s += __shfl_xor(s, 8, 64);
            psum[mi][r] = s;
        }
    if (wc == 0 && r16 == 0) {
        #pragma unroll
        for (int mi = 0; mi < 2; mi++)
            #pragma unroll
            for (int r = 0; r < 4; r++)
                rs[wr * 32 + mi * 16 + kg * 4 + r] = psum[mi][r];
    }
    __syncthreads();
    if (wc == 1 && r16 == 0) {
        #pragma unroll
        for (int mi = 0; mi < 2; mi++)
            #pragma unroll
            for (int r = 0; r < 4; r++)
                rs[wr * 32 + mi * 16 + kg * 4 + r] += psum[mi][r];
    }
    __syncthreads();

    // ---- normalize + store y ----
    unsigned short* yB = yb + ((size_t)b * 4096 + q0) * 256;
    #pragma unroll
    for (int mi = 0; mi < 2; mi++)
        #pragma unroll
        for (int r = 0; r < 4; r++) {
            const int row = wr * 32 + mi * 16 + kg * 4 + r;
            const float rinv = 1.0f / rs[row];
            #pragma unroll
            for (int ni = 0; ni < 8; ni++) {
                const int col = wc * 128 + ni * 16 + r16;
                yB[(size_t)row * 256 + col] = f2bf(yacc[mi][ni][r] * rinv);
            }
        }
}

// 2x2 avgpool NHWC fp32 -> bf16, 4 channels per thread
__global__ __launch_bounds__(256)
void pool2(const float* __restrict__ x, unsigned short* __restrict__ xp)
{
    const int t  = blockIdx.x * 256 + threadIdx.x;   // 8*32*32*128 threads
    const int c4 = t & 127;
    const int j  = (t >> 7) & 31;
    const int i  = (t >> 12) & 31;
    const int b  = t >> 17;
    const float* p = x + ((((size_t)b * 64 + 2 * i) * 64) + 2 * j) * 512 + c4 * 4;
    vfloat4 a0 = *(const vfloat4*)p;
    vfloat4 a1 = *(const vfloat4*)(p + 512);
    vfloat4 a2 = *(const vfloat4*)(p + 64 * 512);
    vfloat4 a3 = *(const vfloat4*)(p + 64 * 512 + 512);
    float r0 = 0.25f * (a0[0] + a1[0] + a2[0] + a3[0]);
    float r1 = 0.25f * (a0[1] + a1[1] + a2[1] + a3[1]);
    float r2 = 0.25f * (a0[2] + a1[2] + a2[2] + a3[2]);
    float r3 = 0.25f * (a0[3] + a1[3] + a2[3] + a3[3]);
    vuint2 o;
    o[0] = (unsigned)f2bf(r0) | ((unsigned)f2bf(r1) << 16);
    o[1] = (unsigned)f2bf(r2) | ((unsigned)f2bf(r3) << 16);
    *(vuint2*)(xp + (size_t)t * 4) = o;
}

// All 4 weight transposes (fp32 [K][N] -> bf16 [N][K]) in ONE kernel.
// 32x32 LDS tiles, coalesced on both sides. Grid: 320 blocks.
__global__ __launch_bounds__(256)
void wprep(const float* __restrict__ wf, const float* __restrict__ wg,
           const float* __restrict__ wh, const float* __restrict__ wo,
           unsigned short* __restrict__ wf_t, unsigned short* __restrict__ wg_t,
           unsigned short* __restrict__ wh_t, unsigned short* __restrict__ wo_t)
{
    __shared__ float tile[32][33];
    int t = blockIdx.x;
    const float* in; unsigned short* out; int K, N;
    if (t < 32)       { in = wf; out = wf_t; K = 512; N = 64;  }
    else if (t < 64)  { in = wg; out = wg_t; K = 512; N = 64;  t -= 32;  }
    else if (t < 192) { in = wh; out = wh_t; K = 512; N = 256; t -= 64;  }
    else              { in = wo; out = wo_t; K = 256; N = 512; t -= 192; }
    const int ntN = N >> 5;
    const int tk = (t / ntN) << 5, tn = (t % ntN) << 5;
    const int tx = threadIdx.x & 31, ty = threadIdx.x >> 5;   // ty 0..7
    #pragma unroll
    for (int s = 0; s < 4; s++)
        tile[ty + s * 8][tx] = in[(size_t)(tk + ty + s * 8) * N + tn + tx];
    __syncthreads();
    #pragma unroll
    for (int s = 0; s < 4; s++)
        out[(size_t)(tn + ty + s * 8) * K + tk + tx] = f2bf(tile[tx][ty + s * 8]);
}

extern "C" void kernel_launch(void* const* d_in, const int* in_sizes, int n_in,
                              void* d_out, int out_size, void* d_ws, size_t ws_size,
                              hipStream_t stream)
{
    const float* x  = (const float*)d_in[0];
    const float* wf = (const float*)d_in[1];
    const float* wg = (const float*)d_in[2];
    const float* wh = (const float*)d_in[3];
    const float* wo = (const float*)d_in[4];
    float* out = (float*)d_out;

    char* ws = (char*)d_ws;
    size_t off = 0;
    auto carve = [&](size_t bytes) {
        char* p = ws + off;
        off = (off + bytes + 255) & ~(size_t)255;
        return p;
    };
    unsigned short* xp   = (unsigned short*)carve(8ll * 1024 * 512 * 2);   // pooled, bf16
    unsigned short* wf_t = (unsigned short*)carve(64 * 512 * 2);
    unsigned short* wg_t = (unsigned short*)carve(64 * 512 * 2);
    unsigned short* wh_t = (unsigned short*)carve(256 * 512 * 2);
    unsigned short* wo_t = (unsigned short*)carve(512 * 256 * 2);
    unsigned short* gb   = (unsigned short*)carve(8ll * 1024 * 64 * 2);    // keys
    unsigned short* ht   = (unsigned short*)carve(8ll * 256 * 1024 * 2);   // values^T
    unsigned short* yb   = (unsigned short*)carve(8ll * 4096 * 256 * 2);

    // weight prep: all 4 transposes in one launch
    wprep<<<dim3(320), 256, 0, stream>>>(wf, wg, wh, wo, wf_t, wg_t, wh_t, wo_t);

    // pooled map (bf16)
    pool2<<<dim3(4096), 256, 0, stream>>>(x, xp);

    // g = xp @ wg   (flattened over batches)
    gemm_bt<1><<<dim3(1, 128, 1), 256, 0, stream>>>(xp, wg_t, gb, 8192, 64, 512, 0, 0, 0);
    // ht_b = wh^T @ xp_b^T  == (xp_b @ wh)^T  directly (no separate transpose)
    gemm_bt<1><<<dim3(16, 4, 8), 256, 0, stream>>>(wh_t, xp, ht, 256, 1024, 512,
                                                   0, 1024LL * 512, 256LL * 1024);

    // fused f-projection + attention: y = softmax((x wf) g^T) h
    flash_attn<<<dim3(256), 512, 0, stream>>>(x, wf_t, gb, ht, yb);

    // out = y @ wo  (fp32 store)
    gemm_bt<0><<<dim3(8, 512, 1), 256, 0, stream>>>(yb, wo_t, out, 32768, 512, 256, 0, 0, 0);
}